// Round 11
// baseline (259.709 us; speedup 1.0000x reference)
//
#include <hip/hip_runtime.h>
#include <math.h>

// SAE hierarchical, R11 = R10 structure + BIT-EXACT R9 rescue arithmetic.
// R10 failure root cause: rescue dot summation ORDER changed (sequential
// 64-chain vs R9's quad-chain + balanced tree) -> fp32 boundary near-ties
// flipped a level-0 top-k selection -> cascaded through level 1 (absmax 4.66).
// In selection problems fp order is semantics. R11: lane-parallel rescue
// (lane c owns candidates c, c+64) computing the dot in R9's exact order:
// q_k = fma(wx,xx, fma(wy,xy, fma(wz,xz, ww*xw))) per quad, then balanced
// binary tree ((q0+q1)+(q2+q3))+... ; thresholds back to 0.25 (R9-proven,
// free under lane-parallel rescue). Keeps merged GEMM loads + decode unroll 2.

#define D64   64
#define ROWS  16
#define CAP   128
#define FTILE 256
#define HID1  4096
#define HID2  2048
#define K1    32
#define K2    16

typedef __attribute__((ext_vector_type(8))) short bf16x8;
typedef __attribute__((ext_vector_type(4))) float f32x4;
typedef unsigned long long u64;

__device__ __forceinline__ unsigned short f2bf(float f) {
    unsigned u = __float_as_uint(f);
    return (unsigned short)((u + 0x7FFFu + ((u >> 16) & 1u)) >> 16);
}

__device__ __forceinline__ float wave_sum_f32(float v) {
#pragma unroll
    for (int off = 32; off > 0; off >>= 1) v += __shfl_xor(v, off, 64);
    return v;
}

// prep: W1|W2 fp32 -> bf16, LINEAR layout. wh[f*64 + k].
__global__ __launch_bounds__(256) void prep_w(const float* __restrict__ W1,
                                              const float* __restrict__ W2,
                                              unsigned short* __restrict__ wh) {
    const int t = blockIdx.x * 256 + threadIdx.x;    // 98304 threads, 1 float4 each
    const int f = t >> 4;
    const float* src = (f < HID1) ? (W1 + (size_t)f * D64)
                                  : (W2 + (size_t)(f - HID1) * D64);
    float4 wv = ((const float4*)src)[t & 15];
    u64 pk = (u64)f2bf(wv.x) | ((u64)f2bf(wv.y) << 16)
           | ((u64)f2bf(wv.z) << 32) | ((u64)f2bf(wv.w) << 48);
    *(u64*)&wh[(size_t)t * 4] = pk;
}

__global__ __launch_bounds__(256) void sae_hier_mfma(
    const float* __restrict__ x,
    const float* __restrict__ W1,  const float* __restrict__ b1,
    const float* __restrict__ Wd1, const float* __restrict__ bd1,
    const float* __restrict__ W2,  const float* __restrict__ b2,
    const float* __restrict__ Wd2, const float* __restrict__ bd2,
    const unsigned short* __restrict__ wh,
    float* __restrict__ out)
{
    __shared__ uint2 s_buf[ROWS * CAP];                       // 16 KB candidates
    __shared__ __align__(16) float s_xf32[ROWS * D64];        // 4 KB exact input
    __shared__ __align__(16) unsigned short s_ah[ROWS * D64]; // 2 KB bf16 A (linear)
    __shared__ float s_sig[ROWS];
    __shared__ float s_thr[ROWS];
    __shared__ float s_scale[ROWS];
    __shared__ int   s_cnt[ROWS];
    __shared__ int   s_act[ROWS];
    __shared__ int   s_anybad;

    const int tid  = threadIdx.x;
    const int lane = tid & 63;
    const int wu   = __builtin_amdgcn_readfirstlane(tid >> 6);  // 4 waves
    const int rowbase = blockIdx.x * ROWS;
    const int g   = lane >> 4;
    const int l15 = lane & 15;

    if (tid < ROWS) { s_cnt[tid] = 0; s_scale[tid] = 1.0f; s_act[tid] = 1; }

    // ---- stage (x - b_dec): fp32 exact + bf16 linear + threshold base ----
    {
        const int r = tid >> 4, q = tid & 15;                 // 16 rows x 16 quads
        float4 a = ((const float4*)x)[(size_t)(rowbase + r) * 16 + q];
        float4 b = ((const float4*)bd1)[q];
        float4 v = make_float4(a.x - b.x, a.y - b.y, a.z - b.z, a.w - b.w);
        ((float4*)s_xf32)[r * 16 + q] = v;
        u64 pk = (u64)f2bf(v.x) | ((u64)f2bf(v.y) << 16)
               | ((u64)f2bf(v.z) << 32) | ((u64)f2bf(v.w) << 48);
        *(u64*)&s_ah[(r * 16 + q) * 4] = pk;
        float ss = fmaf(v.x, v.x, fmaf(v.y, v.y, fmaf(v.z, v.z, v.w * v.w)));
        ss += __shfl_xor(ss, 1, 64); ss += __shfl_xor(ss, 2, 64);
        ss += __shfl_xor(ss, 4, 64); ss += __shfl_xor(ss, 8, 64);
        if (q == 0) s_sig[r] = 0.25f * sqrtf(ss);             // 2*sigma = ||.||/4
    }

#define PUSH4(ACC, BIAS, COLG) { \
    float v0 = fmaxf(ACC[0] + (BIAS), 0.f); \
    float v1 = fmaxf(ACC[1] + (BIAS), 0.f); \
    float v2 = fmaxf(ACC[2] + (BIAS), 0.f); \
    float v3 = fmaxf(ACC[3] + (BIAS), 0.f); \
    if (v0 > t0) { int s = atomicAdd(&s_cnt[g*4+0], 1); if (s < CAP) s_buf[(g*4+0)*CAP+s] = make_uint2(__float_as_uint(v0), (unsigned)(COLG)); } \
    if (v1 > t1) { int s = atomicAdd(&s_cnt[g*4+1], 1); if (s < CAP) s_buf[(g*4+1)*CAP+s] = make_uint2(__float_as_uint(v1), (unsigned)(COLG)); } \
    if (v2 > t2) { int s = atomicAdd(&s_cnt[g*4+2], 1); if (s < CAP) s_buf[(g*4+2)*CAP+s] = make_uint2(__float_as_uint(v2), (unsigned)(COLG)); } \
    if (v3 > t3) { int s = atomicAdd(&s_cnt[g*4+3], 1); if (s < CAP) s_buf[(g*4+3)*CAP+s] = make_uint2(__float_as_uint(v3), (unsigned)(COLG)); } }

#pragma unroll 1
    for (int level = 0; level < 2; ++level) {
        const float* We  = level ? W2  : W1;
        const float* be  = level ? b2  : b1;
        const float* Wd  = level ? Wd2 : Wd1;
        const float* bdv = level ? bd2 : bd1;
        const unsigned short* whL = wh + (level ? (size_t)HID1 * D64 : 0);
        const int KSEL   = level ? K2 : K1;
        const int NPASS  = (level ? HID2 : HID1) / FTILE;

        __syncthreads();

        // ======== barrier-free approx GEMM + threshold push (with retry) ========
#pragma unroll 1
        for (int attempt = 0; attempt < 8; ++attempt) {
            if (tid < ROWS) s_thr[tid] = s_act[tid] ? s_sig[tid] * s_scale[tid] : 3.4e38f;
            __syncthreads();
            bf16x8 a0 = *(const bf16x8*)&s_ah[l15 * D64 + 8 * g];
            bf16x8 a1 = *(const bf16x8*)&s_ah[l15 * D64 + 32 + 8 * g];
            const float t0 = s_thr[g * 4 + 0], t1 = s_thr[g * 4 + 1];
            const float t2 = s_thr[g * 4 + 2], t3 = s_thr[g * 4 + 3];

#pragma unroll 1
            for (int p = 0; p < NPASS; ++p) {
                const int fbase = p * FTILE + wu * 64 + l15;
                const unsigned short* wb = whL + (size_t)fbase * D64;
                const float* bb = be + fbase;
                // one load batch: 8 fragments + 4 biases in flight together
                bf16x8 b00 = *(const bf16x8*)&wb[8 * g];
                bf16x8 b01 = *(const bf16x8*)&wb[8 * g + 32];
                bf16x8 b10 = *(const bf16x8*)&wb[8 * g + 1024];
                bf16x8 b11 = *(const bf16x8*)&wb[8 * g + 1056];
                bf16x8 b20 = *(const bf16x8*)&wb[8 * g + 2048];
                bf16x8 b21 = *(const bf16x8*)&wb[8 * g + 2080];
                bf16x8 b30 = *(const bf16x8*)&wb[8 * g + 3072];
                bf16x8 b31 = *(const bf16x8*)&wb[8 * g + 3104];
                float bias0 = bb[0], bias1 = bb[16], bias2 = bb[32], bias3 = bb[48];
                f32x4 acc0 = {0.f, 0.f, 0.f, 0.f}, acc1 = {0.f, 0.f, 0.f, 0.f};
                f32x4 acc2 = {0.f, 0.f, 0.f, 0.f}, acc3 = {0.f, 0.f, 0.f, 0.f};
                acc0 = __builtin_amdgcn_mfma_f32_16x16x32_bf16(a0, b00, acc0, 0, 0, 0);
                acc0 = __builtin_amdgcn_mfma_f32_16x16x32_bf16(a1, b01, acc0, 0, 0, 0);
                acc1 = __builtin_amdgcn_mfma_f32_16x16x32_bf16(a0, b10, acc1, 0, 0, 0);
                acc1 = __builtin_amdgcn_mfma_f32_16x16x32_bf16(a1, b11, acc1, 0, 0, 0);
                acc2 = __builtin_amdgcn_mfma_f32_16x16x32_bf16(a0, b20, acc2, 0, 0, 0);
                acc2 = __builtin_amdgcn_mfma_f32_16x16x32_bf16(a1, b21, acc2, 0, 0, 0);
                acc3 = __builtin_amdgcn_mfma_f32_16x16x32_bf16(a0, b30, acc3, 0, 0, 0);
                acc3 = __builtin_amdgcn_mfma_f32_16x16x32_bf16(a1, b31, acc3, 0, 0, 0);
                PUSH4(acc0, bias0, fbase)
                PUSH4(acc1, bias1, fbase + 16)
                PUSH4(acc2, bias2, fbase + 32)
                PUSH4(acc3, bias3, fbase + 48)
            }
            __syncthreads();
            if (tid == 0) s_anybad = 0;
            __syncthreads();
            if (tid < ROWS) {
                int c = s_cnt[tid];
                bool lo = (c < KSEL), hi = (c > CAP);
                bool bad = (lo || hi) && (attempt < 7);
                s_act[tid] = bad ? 1 : 0;
                if (bad) { s_scale[tid] *= (lo ? 0.85f : 1.15f); s_cnt[tid] = 0; atomicAdd(&s_anybad, 1); }
            }
            __syncthreads();
            if (s_anybad == 0) break;
        }

        // ==== lane-parallel exact rescue (R9 bit-exact order) + select + decode ====
#pragma unroll 1
        for (int q2 = 0; q2 < 4; ++q2) {
            const int r = wu * 4 + q2;
            int n = s_cnt[r]; if (n > CAP) n = CAP;
            const bool h0 = (lane < n), h1 = (lane + 64 < n);
            unsigned j0 = 0u, j1 = 0u;
            if (h0) j0 = s_buf[r * CAP + lane].y;
            if (h1) j1 = s_buf[r * CAP + lane + 64].y;
            const float4* xrow = ((const float4*)s_xf32) + r * 16;
            const float4* w0p = ((const float4*)We) + (size_t)j0 * 16;
            const float4* w1p = ((const float4*)We) + (size_t)j1 * 16;
            // per-quad chain fma(x, fma(y, fma(z, w*w))) then pairwise combine
            // -- reproduces R9's shfl_xor(1,2,4,8) balanced tree bit-exactly.
            float p0[8], p1[8];
#pragma unroll
            for (int i = 0; i < 8; ++i) {
                float4 xa = xrow[2 * i], xb = xrow[2 * i + 1];
                float4 wa0 = w0p[2 * i], wa1 = w0p[2 * i + 1];
                float4 wb0 = w1p[2 * i], wb1 = w1p[2 * i + 1];
                float qa0 = fmaf(wa0.x, xa.x, fmaf(wa0.y, xa.y, fmaf(wa0.z, xa.z, wa0.w * xa.w)));
                float qa1 = fmaf(wa1.x, xb.x, fmaf(wa1.y, xb.y, fmaf(wa1.z, xb.z, wa1.w * xb.w)));
                float qb0 = fmaf(wb0.x, xa.x, fmaf(wb0.y, xa.y, fmaf(wb0.z, xa.z, wb0.w * xa.w)));
                float qb1 = fmaf(wb1.x, xb.x, fmaf(wb1.y, xb.y, fmaf(wb1.z, xb.z, wb1.w * xb.w)));
                p0[i] = qa0 + qa1;                 // stage 1 (xor 1)
                p1[i] = qb0 + qb1;
            }
            float c00 = p0[0] + p0[1], c01 = p0[2] + p0[3];    // stage 2 (xor 2)
            float c02 = p0[4] + p0[5], c03 = p0[6] + p0[7];
            float c10 = p1[0] + p1[1], c11 = p1[2] + p1[3];
            float c12 = p1[4] + p1[5], c13 = p1[6] + p1[7];
            float d0 = (c00 + c01) + (c02 + c03);              // stages 3,4 (xor 4,8)
            float d1 = (c10 + c11) + (c12 + c13);
            float v0 = fmaxf(d0 + be[j0], 0.f);
            float v1 = fmaxf(d1 + be[j1], 0.f);
            // keys: (exact valbits << 32) | ~idx  (distinct; low index wins ties)
            u64 k0 = h0 ? (((u64)__float_as_uint(v0) << 32) | (unsigned)(~j0)) : 0ull;
            u64 k1 = h1 ? (((u64)__float_as_uint(v1) << 32) | (unsigned)(~j1)) : 0ull;
            // radix select: T = KSEL-th largest key
            u64 T = 0ull;
#pragma unroll 1
            for (int b = 62; b >= 32; --b) {
                u64 cand = T | (1ull << b);
                int c = __popcll(__ballot(k0 >= cand)) + __popcll(__ballot(k1 >= cand));
                if (c >= KSEL) T = cand;
            }
            T |= 0xFFFFF000ull;      // idx < 4096 -> ~idx bits 31..12 always set
#pragma unroll 1
            for (int b = 11; b >= 0; --b) {
                u64 cand = T | (1ull << b);
                int c = __popcll(__ballot(k0 >= cand)) + __popcll(__ballot(k1 >= cand));
                if (c >= KSEL) T = cand;
            }
            // compact exactly-KSEL selected keys into slots [0, KSEL)
            bool f0 = (k0 >= T), f1 = (k1 >= T);
            u64 m0 = __ballot(f0), m1 = __ballot(f1);
            u64 below = (1ull << lane) - 1ull;
            int r0 = __popcll(m0 & below);
            int r1 = __popcll(m0) + __popcll(m1 & below);
            if (f0) s_buf[r * CAP + r0] = make_uint2((unsigned)(k0 >> 32), ~(unsigned)k0);
            if (f1) s_buf[r * CAP + r1] = make_uint2((unsigned)(k1 >> 32), ~(unsigned)k1);
            // decode: rec = bdv + sum z_t * Wd[idx_t] (coalesced row reads)
            float rec = bdv[lane];
#pragma unroll 2
            for (int t = 0; t < KSEL; t += 4) {
                uint2 e0 = s_buf[r * CAP + t + 0];
                uint2 e1 = s_buf[r * CAP + t + 1];
                uint2 e2 = s_buf[r * CAP + t + 2];
                uint2 e3 = s_buf[r * CAP + t + 3];
                float w0 = Wd[(size_t)e0.y * D64 + lane];
                float w1 = Wd[(size_t)e1.y * D64 + lane];
                float w2 = Wd[(size_t)e2.y * D64 + lane];
                float w3 = Wd[(size_t)e3.y * D64 + lane];
                rec = fmaf(__uint_as_float(e0.x), w0, rec);
                rec = fmaf(__uint_as_float(e1.x), w1, rec);
                rec = fmaf(__uint_as_float(e2.x), w2, rec);
                rec = fmaf(__uint_as_float(e3.x), w3, rec);
            }
            if (level == 0) {
                float e = wave_sum_f32(rec * rec);
                if (lane == 0) s_sig[r] = 0.25f * sqrtf(e);   // 2*sigma for level 1
                s_xf32[r * D64 + lane] = rec;                 // exact recon0
                s_ah[r * D64 + lane] = f2bf(rec);             // bf16 A for level 1
            } else {
                float rec0 = s_xf32[r * D64 + lane];
                out[(size_t)(rowbase + r) * D64 + lane] =
                    (1.0f / 1.5f) * rec0 + (0.5f / 1.5f) * rec;
            }
        }
        if (level == 0) {
            __syncthreads();
            if (tid < ROWS) { s_cnt[tid] = 0; s_scale[tid] = 1.0f; s_act[tid] = 1; }
        }
    }
}

extern "C" void kernel_launch(void* const* d_in, const int* in_sizes, int n_in,
                              void* d_out, int out_size, void* d_ws, size_t ws_size,
                              hipStream_t stream) {
    (void)n_in; (void)out_size; (void)ws_size;
    const float* x   = (const float*)d_in[0];
    const float* W1  = (const float*)d_in[1];
    const float* b1  = (const float*)d_in[2];
    const float* Wd1 = (const float*)d_in[3];
    const float* bd1 = (const float*)d_in[4];
    const float* W2  = (const float*)d_in[5];
    const float* b2  = (const float*)d_in[6];
    const float* Wd2 = (const float*)d_in[7];
    const float* bd2 = (const float*)d_in[8];
    unsigned short* wh = (unsigned short*)d_ws;   // 768 KB bf16 linear weights

    prep_w<<<(HID1 + HID2) * 16 / 256, 256, 0, stream>>>(W1, W2, wh);

    const int batch = in_sizes[0] / D64;     // 16384
    const int grid  = batch / ROWS;          // 1024 blocks

    sae_hier_mfma<<<grid, 256, 0, stream>>>(x, W1, b1, Wd1, bd1, W2, b2, Wd2, bd2,
                                            wh, (float*)d_out);
}

// Round 12
// 246.712 us; speedup vs baseline: 1.0527x; 1.0527x over previous
//
#include <hip/hip_runtime.h>
#include <math.h>

// SAE hierarchical, R12 = R11 semantics with register pressure back under the
// 64-VGPR occupancy step. R11 post-mortem: VGPR 44->80 (merged 8-frag GEMM
// batch + rescue p[8] arrays) halved the wave cap (occupancy 42->25%) and
// cost +53us despite correct arithmetic. R12: (1) GEMM loop reverted to R9's
// two 4-fragment sub-blocks (measured 44 VGPR); (2) rescue tree computed
// incrementally per 4-quad group with named vars -- BIT-IDENTICAL association
// ((q0+q1)+(q2+q3)) per group, ((c0+c1)+(c2+c3)) final -- x float4s reused
// across both candidates. Lane-parallel rescue, radix select, decode kept.

#define D64   64
#define ROWS  16
#define CAP   128
#define FTILE 256
#define HID1  4096
#define HID2  2048
#define K1    32
#define K2    16

typedef __attribute__((ext_vector_type(8))) short bf16x8;
typedef __attribute__((ext_vector_type(4))) float f32x4;
typedef unsigned long long u64;

__device__ __forceinline__ unsigned short f2bf(float f) {
    unsigned u = __float_as_uint(f);
    return (unsigned short)((u + 0x7FFFu + ((u >> 16) & 1u)) >> 16);
}

__device__ __forceinline__ float wave_sum_f32(float v) {
#pragma unroll
    for (int off = 32; off > 0; off >>= 1) v += __shfl_xor(v, off, 64);
    return v;
}

// prep: W1|W2 fp32 -> bf16, LINEAR layout. wh[f*64 + k].
__global__ __launch_bounds__(256) void prep_w(const float* __restrict__ W1,
                                              const float* __restrict__ W2,
                                              unsigned short* __restrict__ wh) {
    const int t = blockIdx.x * 256 + threadIdx.x;    // 98304 threads, 1 float4 each
    const int f = t >> 4;
    const float* src = (f < HID1) ? (W1 + (size_t)f * D64)
                                  : (W2 + (size_t)(f - HID1) * D64);
    float4 wv = ((const float4*)src)[t & 15];
    u64 pk = (u64)f2bf(wv.x) | ((u64)f2bf(wv.y) << 16)
           | ((u64)f2bf(wv.z) << 32) | ((u64)f2bf(wv.w) << 48);
    *(u64*)&wh[(size_t)t * 4] = pk;
}

// one 4-quad group for BOTH candidates; association (q0+q1)+(q2+q3).
#define QGRP(J, C0, C1) { \
    float4 xa = xrow[4*(J)+0], xb = xrow[4*(J)+1]; \
    float4 xc = xrow[4*(J)+2], xd = xrow[4*(J)+3]; \
    float4 wA = w0p[4*(J)+0], wB = w0p[4*(J)+1]; \
    float4 wC = w0p[4*(J)+2], wD = w0p[4*(J)+3]; \
    float qa = fmaf(wA.x, xa.x, fmaf(wA.y, xa.y, fmaf(wA.z, xa.z, wA.w * xa.w))); \
    float qb = fmaf(wB.x, xb.x, fmaf(wB.y, xb.y, fmaf(wB.z, xb.z, wB.w * xb.w))); \
    float qc = fmaf(wC.x, xc.x, fmaf(wC.y, xc.y, fmaf(wC.z, xc.z, wC.w * xc.w))); \
    float qd = fmaf(wD.x, xd.x, fmaf(wD.y, xd.y, fmaf(wD.z, xd.z, wD.w * xd.w))); \
    C0 = (qa + qb) + (qc + qd); \
    wA = w1p[4*(J)+0]; wB = w1p[4*(J)+1]; wC = w1p[4*(J)+2]; wD = w1p[4*(J)+3]; \
    qa = fmaf(wA.x, xa.x, fmaf(wA.y, xa.y, fmaf(wA.z, xa.z, wA.w * xa.w))); \
    qb = fmaf(wB.x, xb.x, fmaf(wB.y, xb.y, fmaf(wB.z, xb.z, wB.w * xb.w))); \
    qc = fmaf(wC.x, xc.x, fmaf(wC.y, xc.y, fmaf(wC.z, xc.z, wC.w * xc.w))); \
    qd = fmaf(wD.x, xd.x, fmaf(wD.y, xd.y, fmaf(wD.z, xd.z, wD.w * xd.w))); \
    C1 = (qa + qb) + (qc + qd); }

__global__ __launch_bounds__(256) void sae_hier_mfma(
    const float* __restrict__ x,
    const float* __restrict__ W1,  const float* __restrict__ b1,
    const float* __restrict__ Wd1, const float* __restrict__ bd1,
    const float* __restrict__ W2,  const float* __restrict__ b2,
    const float* __restrict__ Wd2, const float* __restrict__ bd2,
    const unsigned short* __restrict__ wh,
    float* __restrict__ out)
{
    __shared__ uint2 s_buf[ROWS * CAP];                       // 16 KB candidates
    __shared__ __align__(16) float s_xf32[ROWS * D64];        // 4 KB exact input
    __shared__ __align__(16) unsigned short s_ah[ROWS * D64]; // 2 KB bf16 A (linear)
    __shared__ float s_sig[ROWS];
    __shared__ float s_thr[ROWS];
    __shared__ float s_scale[ROWS];
    __shared__ int   s_cnt[ROWS];
    __shared__ int   s_act[ROWS];
    __shared__ int   s_anybad;

    const int tid  = threadIdx.x;
    const int lane = tid & 63;
    const int wu   = __builtin_amdgcn_readfirstlane(tid >> 6);  // 4 waves
    const int rowbase = blockIdx.x * ROWS;
    const int g   = lane >> 4;
    const int l15 = lane & 15;

    if (tid < ROWS) { s_cnt[tid] = 0; s_scale[tid] = 1.0f; s_act[tid] = 1; }

    // ---- stage (x - b_dec): fp32 exact + bf16 linear + threshold base ----
    {
        const int r = tid >> 4, q = tid & 15;                 // 16 rows x 16 quads
        float4 a = ((const float4*)x)[(size_t)(rowbase + r) * 16 + q];
        float4 b = ((const float4*)bd1)[q];
        float4 v = make_float4(a.x - b.x, a.y - b.y, a.z - b.z, a.w - b.w);
        ((float4*)s_xf32)[r * 16 + q] = v;
        u64 pk = (u64)f2bf(v.x) | ((u64)f2bf(v.y) << 16)
               | ((u64)f2bf(v.z) << 32) | ((u64)f2bf(v.w) << 48);
        *(u64*)&s_ah[(r * 16 + q) * 4] = pk;
        float ss = fmaf(v.x, v.x, fmaf(v.y, v.y, fmaf(v.z, v.z, v.w * v.w)));
        ss += __shfl_xor(ss, 1, 64); ss += __shfl_xor(ss, 2, 64);
        ss += __shfl_xor(ss, 4, 64); ss += __shfl_xor(ss, 8, 64);
        if (q == 0) s_sig[r] = 0.25f * sqrtf(ss);             // 2*sigma = ||.||/4
    }

#define PUSH4(ACC, BIAS, COLG) { \
    float v0 = fmaxf(ACC[0] + (BIAS), 0.f); \
    float v1 = fmaxf(ACC[1] + (BIAS), 0.f); \
    float v2 = fmaxf(ACC[2] + (BIAS), 0.f); \
    float v3 = fmaxf(ACC[3] + (BIAS), 0.f); \
    if (v0 > t0) { int s = atomicAdd(&s_cnt[g*4+0], 1); if (s < CAP) s_buf[(g*4+0)*CAP+s] = make_uint2(__float_as_uint(v0), (unsigned)(COLG)); } \
    if (v1 > t1) { int s = atomicAdd(&s_cnt[g*4+1], 1); if (s < CAP) s_buf[(g*4+1)*CAP+s] = make_uint2(__float_as_uint(v1), (unsigned)(COLG)); } \
    if (v2 > t2) { int s = atomicAdd(&s_cnt[g*4+2], 1); if (s < CAP) s_buf[(g*4+2)*CAP+s] = make_uint2(__float_as_uint(v2), (unsigned)(COLG)); } \
    if (v3 > t3) { int s = atomicAdd(&s_cnt[g*4+3], 1); if (s < CAP) s_buf[(g*4+3)*CAP+s] = make_uint2(__float_as_uint(v3), (unsigned)(COLG)); } }

#pragma unroll 1
    for (int level = 0; level < 2; ++level) {
        const float* We  = level ? W2  : W1;
        const float* be  = level ? b2  : b1;
        const float* Wd  = level ? Wd2 : Wd1;
        const float* bdv = level ? bd2 : bd1;
        const unsigned short* whL = wh + (level ? (size_t)HID1 * D64 : 0);
        const int KSEL   = level ? K2 : K1;
        const int NPASS  = (level ? HID2 : HID1) / FTILE;

        __syncthreads();

        // ======== barrier-free approx GEMM + threshold push (with retry) ========
#pragma unroll 1
        for (int attempt = 0; attempt < 8; ++attempt) {
            if (tid < ROWS) s_thr[tid] = s_act[tid] ? s_sig[tid] * s_scale[tid] : 3.4e38f;
            __syncthreads();
            bf16x8 a0 = *(const bf16x8*)&s_ah[l15 * D64 + 8 * g];
            bf16x8 a1 = *(const bf16x8*)&s_ah[l15 * D64 + 32 + 8 * g];
            const float t0 = s_thr[g * 4 + 0], t1 = s_thr[g * 4 + 1];
            const float t2 = s_thr[g * 4 + 2], t3 = s_thr[g * 4 + 3];

#pragma unroll 1
            for (int p = 0; p < NPASS; ++p) {
                const int fbase = p * FTILE + wu * 64 + l15;
                const unsigned short* wb = whL + (size_t)fbase * D64;
                const float* bb = be + fbase;
                {   // subs 0,1 (4 fragments + 2 biases in flight)
                    bf16x8 b00 = *(const bf16x8*)&wb[8 * g];
                    bf16x8 b01 = *(const bf16x8*)&wb[8 * g + 32];
                    bf16x8 b10 = *(const bf16x8*)&wb[8 * g + 1024];
                    bf16x8 b11 = *(const bf16x8*)&wb[8 * g + 1056];
                    float bias0 = bb[0], bias1 = bb[16];
                    f32x4 acc0 = {0.f, 0.f, 0.f, 0.f}, acc1 = {0.f, 0.f, 0.f, 0.f};
                    acc0 = __builtin_amdgcn_mfma_f32_16x16x32_bf16(a0, b00, acc0, 0, 0, 0);
                    acc0 = __builtin_amdgcn_mfma_f32_16x16x32_bf16(a1, b01, acc0, 0, 0, 0);
                    acc1 = __builtin_amdgcn_mfma_f32_16x16x32_bf16(a0, b10, acc1, 0, 0, 0);
                    acc1 = __builtin_amdgcn_mfma_f32_16x16x32_bf16(a1, b11, acc1, 0, 0, 0);
                    PUSH4(acc0, bias0, fbase)
                    PUSH4(acc1, bias1, fbase + 16)
                }
                {   // subs 2,3
                    bf16x8 b20 = *(const bf16x8*)&wb[8 * g + 2048];
                    bf16x8 b21 = *(const bf16x8*)&wb[8 * g + 2080];
                    bf16x8 b30 = *(const bf16x8*)&wb[8 * g + 3072];
                    bf16x8 b31 = *(const bf16x8*)&wb[8 * g + 3104];
                    float bias2 = bb[32], bias3 = bb[48];
                    f32x4 acc2 = {0.f, 0.f, 0.f, 0.f}, acc3 = {0.f, 0.f, 0.f, 0.f};
                    acc2 = __builtin_amdgcn_mfma_f32_16x16x32_bf16(a0, b20, acc2, 0, 0, 0);
                    acc2 = __builtin_amdgcn_mfma_f32_16x16x32_bf16(a1, b21, acc2, 0, 0, 0);
                    acc3 = __builtin_amdgcn_mfma_f32_16x16x32_bf16(a0, b30, acc3, 0, 0, 0);
                    acc3 = __builtin_amdgcn_mfma_f32_16x16x32_bf16(a1, b31, acc3, 0, 0, 0);
                    PUSH4(acc2, bias2, fbase + 32)
                    PUSH4(acc3, bias3, fbase + 48)
                }
            }
            __syncthreads();
            if (tid == 0) s_anybad = 0;
            __syncthreads();
            if (tid < ROWS) {
                int c = s_cnt[tid];
                bool lo = (c < KSEL), hi = (c > CAP);
                bool bad = (lo || hi) && (attempt < 7);
                s_act[tid] = bad ? 1 : 0;
                if (bad) { s_scale[tid] *= (lo ? 0.85f : 1.15f); s_cnt[tid] = 0; atomicAdd(&s_anybad, 1); }
            }
            __syncthreads();
            if (s_anybad == 0) break;
        }

        // ==== lane-parallel exact rescue (bit-exact tree) + select + decode ====
#pragma unroll 1
        for (int q2 = 0; q2 < 4; ++q2) {
            const int r = wu * 4 + q2;
            int n = s_cnt[r]; if (n > CAP) n = CAP;
            const bool h0 = (lane < n), h1 = (lane + 64 < n);
            unsigned j0 = 0u, j1 = 0u;
            if (h0) j0 = s_buf[r * CAP + lane].y;
            if (h1) j1 = s_buf[r * CAP + lane + 64].y;
            const float4* xrow = ((const float4*)s_xf32) + r * 16;
            const float4* w0p = ((const float4*)We) + (size_t)j0 * 16;
            const float4* w1p = ((const float4*)We) + (size_t)j1 * 16;
            float c00, c01, c02, c03, c10, c11, c12, c13;
            QGRP(0, c00, c10)
            QGRP(1, c01, c11)
            QGRP(2, c02, c12)
            QGRP(3, c03, c13)
            float d0 = (c00 + c01) + (c02 + c03);
            float d1 = (c10 + c11) + (c12 + c13);
            float v0 = fmaxf(d0 + be[j0], 0.f);
            float v1 = fmaxf(d1 + be[j1], 0.f);
            // keys: (exact valbits << 32) | ~idx  (distinct; low index wins ties)
            u64 k0 = h0 ? (((u64)__float_as_uint(v0) << 32) | (unsigned)(~j0)) : 0ull;
            u64 k1 = h1 ? (((u64)__float_as_uint(v1) << 32) | (unsigned)(~j1)) : 0ull;
            // radix select: T = KSEL-th largest key
            u64 T = 0ull;
#pragma unroll 1
            for (int b = 62; b >= 32; --b) {
                u64 cand = T | (1ull << b);
                int c = __popcll(__ballot(k0 >= cand)) + __popcll(__ballot(k1 >= cand));
                if (c >= KSEL) T = cand;
            }
            T |= 0xFFFFF000ull;      // idx < 4096 -> ~idx bits 31..12 always set
#pragma unroll 1
            for (int b = 11; b >= 0; --b) {
                u64 cand = T | (1ull << b);
                int c = __popcll(__ballot(k0 >= cand)) + __popcll(__ballot(k1 >= cand));
                if (c >= KSEL) T = cand;
            }
            // compact exactly-KSEL selected keys into slots [0, KSEL)
            bool f0 = (k0 >= T), f1 = (k1 >= T);
            u64 m0 = __ballot(f0), m1 = __ballot(f1);
            u64 below = (1ull << lane) - 1ull;
            int r0 = __popcll(m0 & below);
            int r1 = __popcll(m0) + __popcll(m1 & below);
            if (f0) s_buf[r * CAP + r0] = make_uint2((unsigned)(k0 >> 32), ~(unsigned)k0);
            if (f1) s_buf[r * CAP + r1] = make_uint2((unsigned)(k1 >> 32), ~(unsigned)k1);
            // decode: rec = bdv + sum z_t * Wd[idx_t] (coalesced row reads)
            float rec = bdv[lane];
#pragma unroll 2
            for (int t = 0; t < KSEL; t += 4) {
                uint2 e0 = s_buf[r * CAP + t + 0];
                uint2 e1 = s_buf[r * CAP + t + 1];
                uint2 e2 = s_buf[r * CAP + t + 2];
                uint2 e3 = s_buf[r * CAP + t + 3];
                float w0 = Wd[(size_t)e0.y * D64 + lane];
                float w1 = Wd[(size_t)e1.y * D64 + lane];
                float w2 = Wd[(size_t)e2.y * D64 + lane];
                float w3 = Wd[(size_t)e3.y * D64 + lane];
                rec = fmaf(__uint_as_float(e0.x), w0, rec);
                rec = fmaf(__uint_as_float(e1.x), w1, rec);
                rec = fmaf(__uint_as_float(e2.x), w2, rec);
                rec = fmaf(__uint_as_float(e3.x), w3, rec);
            }
            if (level == 0) {
                float e = wave_sum_f32(rec * rec);
                if (lane == 0) s_sig[r] = 0.25f * sqrtf(e);   // 2*sigma for level 1
                s_xf32[r * D64 + lane] = rec;                 // exact recon0
                s_ah[r * D64 + lane] = f2bf(rec);             // bf16 A for level 1
            } else {
                float rec0 = s_xf32[r * D64 + lane];
                out[(size_t)(rowbase + r) * D64 + lane] =
                    (1.0f / 1.5f) * rec0 + (0.5f / 1.5f) * rec;
            }
        }
        if (level == 0) {
            __syncthreads();
            if (tid < ROWS) { s_cnt[tid] = 0; s_scale[tid] = 1.0f; s_act[tid] = 1; }
        }
    }
}

extern "C" void kernel_launch(void* const* d_in, const int* in_sizes, int n_in,
                              void* d_out, int out_size, void* d_ws, size_t ws_size,
                              hipStream_t stream) {
    (void)n_in; (void)out_size; (void)ws_size;
    const float* x   = (const float*)d_in[0];
    const float* W1  = (const float*)d_in[1];
    const float* b1  = (const float*)d_in[2];
    const float* Wd1 = (const float*)d_in[3];
    const float* bd1 = (const float*)d_in[4];
    const float* W2  = (const float*)d_in[5];
    const float* b2  = (const float*)d_in[6];
    const float* Wd2 = (const float*)d_in[7];
    const float* bd2 = (const float*)d_in[8];
    unsigned short* wh = (unsigned short*)d_ws;   // 768 KB bf16 linear weights

    prep_w<<<(HID1 + HID2) * 16 / 256, 256, 0, stream>>>(W1, W2, wh);

    const int batch = in_sizes[0] / D64;     // 16384
    const int grid  = batch / ROWS;          // 1024 blocks

    sae_hier_mfma<<<grid, 256, 0, stream>>>(x, W1, b1, Wd1, bd1, W2, b2, Wd2, bd2,
                                            wh, (float*)d_out);
}

// Round 13
// 211.241 us; speedup vs baseline: 1.2294x; 1.1679x over previous
//
#include <hip/hip_runtime.h>
#include <math.h>

// SAE hierarchical, R13 = R12 + enforced 64-VGPR cap.
// R12 post-mortem: VGPR 72 (>64 step) kept occupancy at 25%; R9<->R12 isolates
// the step as worth ~50-65us. The scheduler hoists both rescue candidates' W
// loads across QGRP boundaries, inflating peak pressure. R13: (1)
// __launch_bounds__(256, 8) -- the 2nd arg is a CAP (R5 evidence), budget
// 512/8 = 64 VGPR enforced; GEMM needs ~44 (R9-measured) so no hot-loop
// spill possible; (2) sched_barrier(0) between rescue quad-groups pins load
// scheduling so the cap is met without spill. Arithmetic bit-exact to R12.

#define D64   64
#define ROWS  16
#define CAP   128
#define FTILE 256
#define HID1  4096
#define HID2  2048
#define K1    32
#define K2    16

typedef __attribute__((ext_vector_type(8))) short bf16x8;
typedef __attribute__((ext_vector_type(4))) float f32x4;
typedef unsigned long long u64;

__device__ __forceinline__ unsigned short f2bf(float f) {
    unsigned u = __float_as_uint(f);
    return (unsigned short)((u + 0x7FFFu + ((u >> 16) & 1u)) >> 16);
}

__device__ __forceinline__ float wave_sum_f32(float v) {
#pragma unroll
    for (int off = 32; off > 0; off >>= 1) v += __shfl_xor(v, off, 64);
    return v;
}

// prep: W1|W2 fp32 -> bf16, LINEAR layout. wh[f*64 + k].
__global__ __launch_bounds__(256) void prep_w(const float* __restrict__ W1,
                                              const float* __restrict__ W2,
                                              unsigned short* __restrict__ wh) {
    const int t = blockIdx.x * 256 + threadIdx.x;    // 98304 threads, 1 float4 each
    const int f = t >> 4;
    const float* src = (f < HID1) ? (W1 + (size_t)f * D64)
                                  : (W2 + (size_t)(f - HID1) * D64);
    float4 wv = ((const float4*)src)[t & 15];
    u64 pk = (u64)f2bf(wv.x) | ((u64)f2bf(wv.y) << 16)
           | ((u64)f2bf(wv.z) << 32) | ((u64)f2bf(wv.w) << 48);
    *(u64*)&wh[(size_t)t * 4] = pk;
}

// one 4-quad group for BOTH candidates; association (q0+q1)+(q2+q3).
// sched_barrier(0) afterwards stops next-group load hoisting (VGPR pressure).
#define QGRP(J, C0, C1) { \
    float4 xa = xrow[4*(J)+0], xb = xrow[4*(J)+1]; \
    float4 xc = xrow[4*(J)+2], xd = xrow[4*(J)+3]; \
    float4 wA = w0p[4*(J)+0], wB = w0p[4*(J)+1]; \
    float4 wC = w0p[4*(J)+2], wD = w0p[4*(J)+3]; \
    float qa = fmaf(wA.x, xa.x, fmaf(wA.y, xa.y, fmaf(wA.z, xa.z, wA.w * xa.w))); \
    float qb = fmaf(wB.x, xb.x, fmaf(wB.y, xb.y, fmaf(wB.z, xb.z, wB.w * xb.w))); \
    float qc = fmaf(wC.x, xc.x, fmaf(wC.y, xc.y, fmaf(wC.z, xc.z, wC.w * xc.w))); \
    float qd = fmaf(wD.x, xd.x, fmaf(wD.y, xd.y, fmaf(wD.z, xd.z, wD.w * xd.w))); \
    C0 = (qa + qb) + (qc + qd); \
    wA = w1p[4*(J)+0]; wB = w1p[4*(J)+1]; wC = w1p[4*(J)+2]; wD = w1p[4*(J)+3]; \
    qa = fmaf(wA.x, xa.x, fmaf(wA.y, xa.y, fmaf(wA.z, xa.z, wA.w * xa.w))); \
    qb = fmaf(wB.x, xb.x, fmaf(wB.y, xb.y, fmaf(wB.z, xb.z, wB.w * xb.w))); \
    qc = fmaf(wC.x, xc.x, fmaf(wC.y, xc.y, fmaf(wC.z, xc.z, wC.w * xc.w))); \
    qd = fmaf(wD.x, xd.x, fmaf(wD.y, xd.y, fmaf(wD.z, xd.z, wD.w * xd.w))); \
    C1 = (qa + qb) + (qc + qd); } \
    __builtin_amdgcn_sched_barrier(0);

__global__ __launch_bounds__(256, 8) void sae_hier_mfma(
    const float* __restrict__ x,
    const float* __restrict__ W1,  const float* __restrict__ b1,
    const float* __restrict__ Wd1, const float* __restrict__ bd1,
    const float* __restrict__ W2,  const float* __restrict__ b2,
    const float* __restrict__ Wd2, const float* __restrict__ bd2,
    const unsigned short* __restrict__ wh,
    float* __restrict__ out)
{
    __shared__ uint2 s_buf[ROWS * CAP];                       // 16 KB candidates
    __shared__ __align__(16) float s_xf32[ROWS * D64];        // 4 KB exact input
    __shared__ __align__(16) unsigned short s_ah[ROWS * D64]; // 2 KB bf16 A (linear)
    __shared__ float s_sig[ROWS];
    __shared__ float s_thr[ROWS];
    __shared__ float s_scale[ROWS];
    __shared__ int   s_cnt[ROWS];
    __shared__ int   s_act[ROWS];
    __shared__ int   s_anybad;

    const int tid  = threadIdx.x;
    const int lane = tid & 63;
    const int wu   = __builtin_amdgcn_readfirstlane(tid >> 6);  // 4 waves
    const int rowbase = blockIdx.x * ROWS;
    const int g   = lane >> 4;
    const int l15 = lane & 15;

    if (tid < ROWS) { s_cnt[tid] = 0; s_scale[tid] = 1.0f; s_act[tid] = 1; }

    // ---- stage (x - b_dec): fp32 exact + bf16 linear + threshold base ----
    {
        const int r = tid >> 4, q = tid & 15;                 // 16 rows x 16 quads
        float4 a = ((const float4*)x)[(size_t)(rowbase + r) * 16 + q];
        float4 b = ((const float4*)bd1)[q];
        float4 v = make_float4(a.x - b.x, a.y - b.y, a.z - b.z, a.w - b.w);
        ((float4*)s_xf32)[r * 16 + q] = v;
        u64 pk = (u64)f2bf(v.x) | ((u64)f2bf(v.y) << 16)
               | ((u64)f2bf(v.z) << 32) | ((u64)f2bf(v.w) << 48);
        *(u64*)&s_ah[(r * 16 + q) * 4] = pk;
        float ss = fmaf(v.x, v.x, fmaf(v.y, v.y, fmaf(v.z, v.z, v.w * v.w)));
        ss += __shfl_xor(ss, 1, 64); ss += __shfl_xor(ss, 2, 64);
        ss += __shfl_xor(ss, 4, 64); ss += __shfl_xor(ss, 8, 64);
        if (q == 0) s_sig[r] = 0.25f * sqrtf(ss);             // 2*sigma = ||.||/4
    }

#define PUSH4(ACC, BIAS, COLG) { \
    float v0 = fmaxf(ACC[0] + (BIAS), 0.f); \
    float v1 = fmaxf(ACC[1] + (BIAS), 0.f); \
    float v2 = fmaxf(ACC[2] + (BIAS), 0.f); \
    float v3 = fmaxf(ACC[3] + (BIAS), 0.f); \
    if (v0 > t0) { int s = atomicAdd(&s_cnt[g*4+0], 1); if (s < CAP) s_buf[(g*4+0)*CAP+s] = make_uint2(__float_as_uint(v0), (unsigned)(COLG)); } \
    if (v1 > t1) { int s = atomicAdd(&s_cnt[g*4+1], 1); if (s < CAP) s_buf[(g*4+1)*CAP+s] = make_uint2(__float_as_uint(v1), (unsigned)(COLG)); } \
    if (v2 > t2) { int s = atomicAdd(&s_cnt[g*4+2], 1); if (s < CAP) s_buf[(g*4+2)*CAP+s] = make_uint2(__float_as_uint(v2), (unsigned)(COLG)); } \
    if (v3 > t3) { int s = atomicAdd(&s_cnt[g*4+3], 1); if (s < CAP) s_buf[(g*4+3)*CAP+s] = make_uint2(__float_as_uint(v3), (unsigned)(COLG)); } }

#pragma unroll 1
    for (int level = 0; level < 2; ++level) {
        const float* We  = level ? W2  : W1;
        const float* be  = level ? b2  : b1;
        const float* Wd  = level ? Wd2 : Wd1;
        const float* bdv = level ? bd2 : bd1;
        const unsigned short* whL = wh + (level ? (size_t)HID1 * D64 : 0);
        const int KSEL   = level ? K2 : K1;
        const int NPASS  = (level ? HID2 : HID1) / FTILE;

        __syncthreads();

        // ======== barrier-free approx GEMM + threshold push (with retry) ========
#pragma unroll 1
        for (int attempt = 0; attempt < 8; ++attempt) {
            if (tid < ROWS) s_thr[tid] = s_act[tid] ? s_sig[tid] * s_scale[tid] : 3.4e38f;
            __syncthreads();
            bf16x8 a0 = *(const bf16x8*)&s_ah[l15 * D64 + 8 * g];
            bf16x8 a1 = *(const bf16x8*)&s_ah[l15 * D64 + 32 + 8 * g];
            const float t0 = s_thr[g * 4 + 0], t1 = s_thr[g * 4 + 1];
            const float t2 = s_thr[g * 4 + 2], t3 = s_thr[g * 4 + 3];

#pragma unroll 1
            for (int p = 0; p < NPASS; ++p) {
                const int fbase = p * FTILE + wu * 64 + l15;
                const unsigned short* wb = whL + (size_t)fbase * D64;
                const float* bb = be + fbase;
                {   // subs 0,1 (4 fragments + 2 biases in flight)
                    bf16x8 b00 = *(const bf16x8*)&wb[8 * g];
                    bf16x8 b01 = *(const bf16x8*)&wb[8 * g + 32];
                    bf16x8 b10 = *(const bf16x8*)&wb[8 * g + 1024];
                    bf16x8 b11 = *(const bf16x8*)&wb[8 * g + 1056];
                    float bias0 = bb[0], bias1 = bb[16];
                    f32x4 acc0 = {0.f, 0.f, 0.f, 0.f}, acc1 = {0.f, 0.f, 0.f, 0.f};
                    acc0 = __builtin_amdgcn_mfma_f32_16x16x32_bf16(a0, b00, acc0, 0, 0, 0);
                    acc0 = __builtin_amdgcn_mfma_f32_16x16x32_bf16(a1, b01, acc0, 0, 0, 0);
                    acc1 = __builtin_amdgcn_mfma_f32_16x16x32_bf16(a0, b10, acc1, 0, 0, 0);
                    acc1 = __builtin_amdgcn_mfma_f32_16x16x32_bf16(a1, b11, acc1, 0, 0, 0);
                    PUSH4(acc0, bias0, fbase)
                    PUSH4(acc1, bias1, fbase + 16)
                }
                {   // subs 2,3
                    bf16x8 b20 = *(const bf16x8*)&wb[8 * g + 2048];
                    bf16x8 b21 = *(const bf16x8*)&wb[8 * g + 2080];
                    bf16x8 b30 = *(const bf16x8*)&wb[8 * g + 3072];
                    bf16x8 b31 = *(const bf16x8*)&wb[8 * g + 3104];
                    float bias2 = bb[32], bias3 = bb[48];
                    f32x4 acc2 = {0.f, 0.f, 0.f, 0.f}, acc3 = {0.f, 0.f, 0.f, 0.f};
                    acc2 = __builtin_amdgcn_mfma_f32_16x16x32_bf16(a0, b20, acc2, 0, 0, 0);
                    acc2 = __builtin_amdgcn_mfma_f32_16x16x32_bf16(a1, b21, acc2, 0, 0, 0);
                    acc3 = __builtin_amdgcn_mfma_f32_16x16x32_bf16(a0, b30, acc3, 0, 0, 0);
                    acc3 = __builtin_amdgcn_mfma_f32_16x16x32_bf16(a1, b31, acc3, 0, 0, 0);
                    PUSH4(acc2, bias2, fbase + 32)
                    PUSH4(acc3, bias3, fbase + 48)
                }
            }
            __syncthreads();
            if (tid == 0) s_anybad = 0;
            __syncthreads();
            if (tid < ROWS) {
                int c = s_cnt[tid];
                bool lo = (c < KSEL), hi = (c > CAP);
                bool bad = (lo || hi) && (attempt < 7);
                s_act[tid] = bad ? 1 : 0;
                if (bad) { s_scale[tid] *= (lo ? 0.85f : 1.15f); s_cnt[tid] = 0; atomicAdd(&s_anybad, 1); }
            }
            __syncthreads();
            if (s_anybad == 0) break;
        }

        // ==== lane-parallel exact rescue (bit-exact tree) + select + decode ====
#pragma unroll 1
        for (int q2 = 0; q2 < 4; ++q2) {
            const int r = wu * 4 + q2;
            int n = s_cnt[r]; if (n > CAP) n = CAP;
            const bool h0 = (lane < n), h1 = (lane + 64 < n);
            unsigned j0 = 0u, j1 = 0u;
            if (h0) j0 = s_buf[r * CAP + lane].y;
            if (h1) j1 = s_buf[r * CAP + lane + 64].y;
            const float4* xrow = ((const float4*)s_xf32) + r * 16;
            const float4* w0p = ((const float4*)We) + (size_t)j0 * 16;
            const float4* w1p = ((const float4*)We) + (size_t)j1 * 16;
            float c00, c01, c02, c03, c10, c11, c12, c13;
            QGRP(0, c00, c10)
            QGRP(1, c01, c11)
            QGRP(2, c02, c12)
            QGRP(3, c03, c13)
            float d0 = (c00 + c01) + (c02 + c03);
            float d1 = (c10 + c11) + (c12 + c13);
            float v0 = fmaxf(d0 + be[j0], 0.f);
            float v1 = fmaxf(d1 + be[j1], 0.f);
            // keys: (exact valbits << 32) | ~idx  (distinct; low index wins ties)
            u64 k0 = h0 ? (((u64)__float_as_uint(v0) << 32) | (unsigned)(~j0)) : 0ull;
            u64 k1 = h1 ? (((u64)__float_as_uint(v1) << 32) | (unsigned)(~j1)) : 0ull;
            // radix select: T = KSEL-th largest key
            u64 T = 0ull;
#pragma unroll 1
            for (int b = 62; b >= 32; --b) {
                u64 cand = T | (1ull << b);
                int c = __popcll(__ballot(k0 >= cand)) + __popcll(__ballot(k1 >= cand));
                if (c >= KSEL) T = cand;
            }
            T |= 0xFFFFF000ull;      // idx < 4096 -> ~idx bits 31..12 always set
#pragma unroll 1
            for (int b = 11; b >= 0; --b) {
                u64 cand = T | (1ull << b);
                int c = __popcll(__ballot(k0 >= cand)) + __popcll(__ballot(k1 >= cand));
                if (c >= KSEL) T = cand;
            }
            // compact exactly-KSEL selected keys into slots [0, KSEL)
            bool f0 = (k0 >= T), f1 = (k1 >= T);
            u64 m0 = __ballot(f0), m1 = __ballot(f1);
            u64 below = (1ull << lane) - 1ull;
            int r0 = __popcll(m0 & below);
            int r1 = __popcll(m0) + __popcll(m1 & below);
            if (f0) s_buf[r * CAP + r0] = make_uint2((unsigned)(k0 >> 32), ~(unsigned)k0);
            if (f1) s_buf[r * CAP + r1] = make_uint2((unsigned)(k1 >> 32), ~(unsigned)k1);
            // decode: rec = bdv + sum z_t * Wd[idx_t] (coalesced row reads)
            float rec = bdv[lane];
#pragma unroll 2
            for (int t = 0; t < KSEL; t += 4) {
                uint2 e0 = s_buf[r * CAP + t + 0];
                uint2 e1 = s_buf[r * CAP + t + 1];
                uint2 e2 = s_buf[r * CAP + t + 2];
                uint2 e3 = s_buf[r * CAP + t + 3];
                float w0 = Wd[(size_t)e0.y * D64 + lane];
                float w1 = Wd[(size_t)e1.y * D64 + lane];
                float w2 = Wd[(size_t)e2.y * D64 + lane];
                float w3 = Wd[(size_t)e3.y * D64 + lane];
                rec = fmaf(__uint_as_float(e0.x), w0, rec);
                rec = fmaf(__uint_as_float(e1.x), w1, rec);
                rec = fmaf(__uint_as_float(e2.x), w2, rec);
                rec = fmaf(__uint_as_float(e3.x), w3, rec);
            }
            if (level == 0) {
                float e = wave_sum_f32(rec * rec);
                if (lane == 0) s_sig[r] = 0.25f * sqrtf(e);   // 2*sigma for level 1
                s_xf32[r * D64 + lane] = rec;                 // exact recon0
                s_ah[r * D64 + lane] = f2bf(rec);             // bf16 A for level 1
            } else {
                float rec0 = s_xf32[r * D64 + lane];
                out[(size_t)(rowbase + r) * D64 + lane] =
                    (1.0f / 1.5f) * rec0 + (0.5f / 1.5f) * rec;
            }
        }
        if (level == 0) {
            __syncthreads();
            if (tid < ROWS) { s_cnt[tid] = 0; s_scale[tid] = 1.0f; s_act[tid] = 1; }
        }
    }
}

extern "C" void kernel_launch(void* const* d_in, const int* in_sizes, int n_in,
                              void* d_out, int out_size, void* d_ws, size_t ws_size,
                              hipStream_t stream) {
    (void)n_in; (void)out_size; (void)ws_size;
    const float* x   = (const float*)d_in[0];
    const float* W1  = (const float*)d_in[1];
    const float* b1  = (const float*)d_in[2];
    const float* Wd1 = (const float*)d_in[3];
    const float* bd1 = (const float*)d_in[4];
    const float* W2  = (const float*)d_in[5];
    const float* b2  = (const float*)d_in[6];
    const float* Wd2 = (const float*)d_in[7];
    const float* bd2 = (const float*)d_in[8];
    unsigned short* wh = (unsigned short*)d_ws;   // 768 KB bf16 linear weights

    prep_w<<<(HID1 + HID2) * 16 / 256, 256, 0, stream>>>(W1, W2, wh);

    const int batch = in_sizes[0] / D64;     // 16384
    const int grid  = batch / ROWS;          // 1024 blocks

    sae_hier_mfma<<<grid, 256, 0, stream>>>(x, W1, b1, Wd1, bd1, W2, b2, Wd2, bd2,
                                            wh, (float*)d_out);
}